// Round 1
// baseline (730.853 us; speedup 1.0000x reference)
//
#include <hip/hip_runtime.h>
#include <hip/hip_bf16.h>

#define TT    1024
#define BATCH 512
#define HH    128
#define II    64
#define BC    16
#define NTHR  512
#define CHUNK 8
#define XROW  72   // shorts per x row: 64 data + 8 pad (144B, breaks bank conflicts)
#define HROW  136  // shorts per h row: 128 data + 8 pad (272B)

typedef __attribute__((ext_vector_type(8))) short bhalf8;
typedef __attribute__((ext_vector_type(4))) short bhalf4;
typedef __attribute__((ext_vector_type(4))) float f32x4;

static __device__ __forceinline__ unsigned pack2bf(float lo, float hi) {
  unsigned a = (unsigned)__builtin_bit_cast(unsigned short, __float2bfloat16(lo));
  unsigned b = (unsigned)__builtin_bit_cast(unsigned short, __float2bfloat16(hi));
  return a | (b << 16);
}
static __device__ __forceinline__ float bf2f(short s) {
  return __builtin_bit_cast(float, ((unsigned)(unsigned short)s) << 16);
}
static __device__ __forceinline__ f32x4 mfma16(bhalf8 a, bhalf8 b, f32x4 c) {
  return __builtin_amdgcn_mfma_f32_16x16x32_bf16(a, b, c, 0, 0, 0);
}
static __device__ __forceinline__ bhalf8 packrow8(const float* p) {
  union { bhalf8 v; unsigned u[4]; } cv;
  cv.u[0] = pack2bf(p[0], p[1]);
  cv.u[1] = pack2bf(p[2], p[3]);
  cv.u[2] = pack2bf(p[4], p[5]);
  cv.u[3] = pack2bf(p[6], p[7]);
  return cv.v;
}

// One WG of 8 waves owns 16 batch samples for the whole sequence.
// Wave wv owns h-dims [wv*16, wv*16+16): computes r,z,hn,xn tiles for them.
// MFMA: D[g,b] = W[g,k] * h^T[k,b]  (A = weights, resident in VGPRs; B = h/x from LDS)
// D layout (m89-verified): col = lane&15 (batch), row = (lane>>4)*4 + reg (gate dim)
// A/B frag: row/col = lane&15, k = (lane>>4)*8 + j (8 contiguous k; matches m92's
// contiguous bf16x8 vec-load, ref-checked in learn_hip)
__global__ __launch_bounds__(NTHR, 2) void gru_fused(
    const float* __restrict__ xin, const float* __restrict__ Wih,
    const float* __restrict__ Whh, const float* __restrict__ bih,
    const float* __restrict__ bhh, const float* __restrict__ Wfc,
    const float* __restrict__ bfc, float* __restrict__ out)
{
  __shared__ short xsh[2][CHUNK][BC * XROW];  // x staged as bf16, double-buffered chunks
  __shared__ short hsh[2][BC * HROW];         // h state, double-buffered per step

  const int tid = threadIdx.x;
  const int lane = tid & 63;
  const int wv = tid >> 6;
  const int q = lane >> 4;
  const int c15 = lane & 15;
  const int b0 = blockIdx.x * BC;

  // ---- resident weight fragments (A-operand layout) ----
  bhalf8 whh[3][4];  // [gate][k-tile of 32], rows = gate*128 + wv*16 + c15
  bhalf8 wih[3][2];
#pragma unroll
  for (int g = 0; g < 3; ++g) {
    const int grow = g * HH + wv * 16 + c15;
#pragma unroll
    for (int kt = 0; kt < 4; ++kt)
      whh[g][kt] = packrow8(Whh + grow * HH + kt * 32 + q * 8);
#pragma unroll
    for (int kt = 0; kt < 2; ++kt)
      wih[g][kt] = packrow8(Wih + grow * II + kt * 32 + q * 8);
  }

  // biases folded into accumulator init (row = this lane's gate dim)
  f32x4 bias_r, bias_z, bias_hn, bias_xn;
#pragma unroll
  for (int r = 0; r < 4; ++r) {
    const int d = wv * 16 + q * 4 + r;
    bias_r[r]  = bih[d] + bhh[d];
    bias_z[r]  = bih[HH + d] + bhh[HH + d];
    bias_xn[r] = bih[2 * HH + d];
    bias_hn[r] = bhh[2 * HH + d];
  }

  // h0 = 0
  for (int i = tid; i < BC * HROW; i += NTHR) hsh[0][i] = 0;

  float4 xl[4];
  // ---- stage chunk 0 (global fp32 -> bf16 LDS) ----
#pragma unroll
  for (int i = 0; i < 2; ++i) {
    const int L = tid + NTHR * i;
    const int tp = L >> 7, b = (L >> 3) & 15, g8 = L & 7;
    const float* src = xin + (size_t)(b0 + b) * (TT * II) + tp * II + g8 * 8;
    xl[2 * i]     = *(const float4*)src;
    xl[2 * i + 1] = *(const float4*)(src + 4);
  }
#pragma unroll
  for (int i = 0; i < 2; ++i) {
    const int L = tid + NTHR * i;
    const int tp = L >> 7, b = (L >> 3) & 15, g8 = L & 7;
    union { bhalf8 v; unsigned u[4]; } cv;
    cv.u[0] = pack2bf(xl[2 * i].x, xl[2 * i].y);
    cv.u[1] = pack2bf(xl[2 * i].z, xl[2 * i].w);
    cv.u[2] = pack2bf(xl[2 * i + 1].x, xl[2 * i + 1].y);
    cv.u[3] = pack2bf(xl[2 * i + 1].z, xl[2 * i + 1].w);
    *(bhalf8*)&xsh[0][tp][b * XROW + g8 * 8] = cv.v;
  }
  __syncthreads();

  f32x4 hprev = {0.f, 0.f, 0.f, 0.f};

#pragma unroll 1
  for (int c = 0; c < TT / CHUNK; ++c) {
    const int more = (c + 1 < TT / CHUNK);
    if (more) {  // issue next-chunk global loads early; land mid-chunk
      const int t0 = (c + 1) * CHUNK;
#pragma unroll
      for (int i = 0; i < 2; ++i) {
        const int L = tid + NTHR * i;
        const int tp = L >> 7, b = (L >> 3) & 15, g8 = L & 7;
        const float* src = xin + (size_t)(b0 + b) * (TT * II) + (t0 + tp) * II + g8 * 8;
        xl[2 * i]     = *(const float4*)src;
        xl[2 * i + 1] = *(const float4*)(src + 4);
      }
    }
#pragma unroll
    for (int tp = 0; tp < CHUNK; ++tp) {
      const int t = c * CHUNK + tp;
      const int hb = t & 1;
      // h B-frags: 4 x ds_read_b128 (2-way bank conflict max, padded rows)
      const short* hrow = &hsh[hb][c15 * HROW];
      bhalf8 hf0 = *(const bhalf8*)(hrow + q * 8);
      bhalf8 hf1 = *(const bhalf8*)(hrow + 32 + q * 8);
      bhalf8 hf2 = *(const bhalf8*)(hrow + 64 + q * 8);
      bhalf8 hf3 = *(const bhalf8*)(hrow + 96 + q * 8);
      const short* xrow = &xsh[c & 1][tp][c15 * XROW];
      bhalf8 xf0 = *(const bhalf8*)(xrow + q * 8);
      bhalf8 xf1 = *(const bhalf8*)(xrow + 32 + q * 8);

      f32x4 ar = bias_r, az = bias_z, ahn = bias_hn, axn = bias_xn;
      ar  = mfma16(whh[0][0], hf0, ar);  ar  = mfma16(whh[0][1], hf1, ar);
      ar  = mfma16(whh[0][2], hf2, ar);  ar  = mfma16(whh[0][3], hf3, ar);
      az  = mfma16(whh[1][0], hf0, az);  az  = mfma16(whh[1][1], hf1, az);
      az  = mfma16(whh[1][2], hf2, az);  az  = mfma16(whh[1][3], hf3, az);
      ahn = mfma16(whh[2][0], hf0, ahn); ahn = mfma16(whh[2][1], hf1, ahn);
      ahn = mfma16(whh[2][2], hf2, ahn); ahn = mfma16(whh[2][3], hf3, ahn);
      ar  = mfma16(wih[0][0], xf0, ar);  ar  = mfma16(wih[0][1], xf1, ar);
      az  = mfma16(wih[1][0], xf0, az);  az  = mfma16(wih[1][1], xf1, az);
      axn = mfma16(wih[2][0], xf0, axn); axn = mfma16(wih[2][1], xf1, axn);

      // gates: lane-local (4 consecutive h-dims, one batch col); h kept fp32
#pragma unroll
      for (int r = 0; r < 4; ++r) {
        const float rg = __builtin_amdgcn_rcpf(1.0f + __expf(-ar[r]));
        const float zg = __builtin_amdgcn_rcpf(1.0f + __expf(-az[r]));
        const float na = fmaf(rg, ahn[r], axn[r]);
        const float e2 = __expf(na + na);
        const float ng = 1.0f - 2.0f * __builtin_amdgcn_rcpf(e2 + 1.0f);
        hprev[r] = fmaf(zg, hprev[r] - ng, ng);
      }

      // mid-chunk: write next chunk's x into the other LDS buffer
      if (tp == 4 && more) {
#pragma unroll
        for (int i = 0; i < 2; ++i) {
          const int L = tid + NTHR * i;
          const int tpp = L >> 7, b = (L >> 3) & 15, g8 = L & 7;
          union { bhalf8 v; unsigned u[4]; } cv;
          cv.u[0] = pack2bf(xl[2 * i].x, xl[2 * i].y);
          cv.u[1] = pack2bf(xl[2 * i].z, xl[2 * i].w);
          cv.u[2] = pack2bf(xl[2 * i + 1].x, xl[2 * i + 1].y);
          cv.u[3] = pack2bf(xl[2 * i + 1].z, xl[2 * i + 1].w);
          *(bhalf8*)&xsh[(c + 1) & 1][tpp][b * XROW + g8 * 8] = cv.v;
        }
      }

      // publish h_new (4 consecutive dims -> one ds_write_b64)
      union { bhalf4 v; unsigned u[2]; } hp;
      hp.u[0] = pack2bf(hprev[0], hprev[1]);
      hp.u[1] = pack2bf(hprev[2], hprev[3]);
      *(bhalf4*)&hsh[hb ^ 1][c15 * HROW + wv * 16 + q * 4] = hp.v;
      __syncthreads();
    }
  }

  // ---- FC head: out[16,51] from h_T (in hsh[0], since T is even) ----
  for (int idx = tid; idx < BC * 51; idx += NTHR) {
    const int bb = idx / 51;
    const int o = idx - bb * 51;
    const float* wf = Wfc + o * HH;
    const short* hr = &hsh[0][bb * HROW];
    float s = bfc[o];
#pragma unroll
    for (int d = 0; d < HH; d += 4) {
      const float4 wvv = *(const float4*)(wf + d);
      s += bf2f(hr[d]) * wvv.x + bf2f(hr[d + 1]) * wvv.y
         + bf2f(hr[d + 2]) * wvv.z + bf2f(hr[d + 3]) * wvv.w;
    }
    out[(size_t)(b0 + bb) * 51 + o] = s;
  }
}

extern "C" void kernel_launch(void* const* d_in, const int* in_sizes, int n_in,
                              void* d_out, int out_size, void* d_ws, size_t ws_size,
                              hipStream_t stream) {
  const float* xin = (const float*)d_in[0];
  const float* Wih = (const float*)d_in[1];
  const float* Whh = (const float*)d_in[2];
  const float* bih = (const float*)d_in[3];
  const float* bhh = (const float*)d_in[4];
  const float* Wfc = (const float*)d_in[5];
  const float* bfc = (const float*)d_in[6];
  float* o = (float*)d_out;
  hipLaunchKernelGGL(gru_fused, dim3(BATCH / BC), dim3(NTHR), 0, stream,
                     xin, Wih, Whh, bih, bhh, Wfc, bfc, o);
}

// Round 2
// 728.795 us; speedup vs baseline: 1.0028x; 1.0028x over previous
//
#include <hip/hip_runtime.h>
#include <hip/hip_bf16.h>

#define TT    1024
#define BATCH 512
#define HH    128
#define II    64
#define BC    16
#define NTHR  512
#define CHUNK 8
#define XROW  72   // shorts per x row: 64 data + 8 pad (144B, breaks bank conflicts)
#define HROW  136  // shorts per h row: 128 data + 8 pad (272B)

typedef __attribute__((ext_vector_type(8))) short bhalf8;
typedef __attribute__((ext_vector_type(4))) short bhalf4;
typedef __attribute__((ext_vector_type(4))) float f32x4;

static __device__ __forceinline__ unsigned pack2bf(float lo, float hi) {
  unsigned a = (unsigned)__builtin_bit_cast(unsigned short, __float2bfloat16(lo));
  unsigned b = (unsigned)__builtin_bit_cast(unsigned short, __float2bfloat16(hi));
  return a | (b << 16);
}
static __device__ __forceinline__ float bf2f(short s) {
  return __builtin_bit_cast(float, ((unsigned)(unsigned short)s) << 16);
}
static __device__ __forceinline__ f32x4 mfma16(bhalf8 a, bhalf8 b, f32x4 c) {
  return __builtin_amdgcn_mfma_f32_16x16x32_bf16(a, b, c, 0, 0, 0);
}
static __device__ __forceinline__ bhalf8 packrow8(const float* p) {
  union { bhalf8 v; unsigned u[4]; } cv;
  cv.u[0] = pack2bf(p[0], p[1]);
  cv.u[1] = pack2bf(p[2], p[3]);
  cv.u[2] = pack2bf(p[4], p[5]);
  cv.u[3] = pack2bf(p[6], p[7]);
  return cv.v;
}
// barrier that does NOT drain vmcnt: keeps the x global prefetch in flight
// across step barriers (default __syncthreads emits s_waitcnt vmcnt(0) which
// exposed ~900cy HBM latency once per chunk). lgkmcnt(0) still orders all
// ds_write/ds_read for h/x correctness.
static __device__ __forceinline__ void bar_lgkm() {
  asm volatile("s_waitcnt lgkmcnt(0)\n\ts_barrier" ::: "memory");
}

// One WG of 8 waves owns 16 batch samples for the whole sequence.
// Wave wv owns h-dims [wv*16, wv*16+16). MFMA: D[g,b] = W[g,k] * h^T[k,b]
// Step schedule (software-pipelined): acc enters the step already holding
// bias + x-side MFMAs; post-barrier work is only the 12 h-side MFMAs.
__global__ __launch_bounds__(NTHR, 2) void gru_fused(
    const float* __restrict__ xin, const float* __restrict__ Wih,
    const float* __restrict__ Whh, const float* __restrict__ bih,
    const float* __restrict__ bhh, const float* __restrict__ Wfc,
    const float* __restrict__ bfc, float* __restrict__ out)
{
  __shared__ short xsh[2][CHUNK][BC * XROW];  // x staged as bf16, double-buffered chunks
  __shared__ short hsh[2][BC * HROW];         // h state, double-buffered per step

  const int tid = threadIdx.x;
  const int lane = tid & 63;
  const int wv = tid >> 6;
  const int q = lane >> 4;
  const int c15 = lane & 15;
  const int b0 = blockIdx.x * BC;

  // ---- resident weight fragments (A-operand layout) ----
  bhalf8 whh[3][4];  // [gate][k-tile of 32], rows = gate*128 + wv*16 + c15
  bhalf8 wih[3][2];
#pragma unroll
  for (int g = 0; g < 3; ++g) {
    const int grow = g * HH + wv * 16 + c15;
#pragma unroll
    for (int kt = 0; kt < 4; ++kt)
      whh[g][kt] = packrow8(Whh + grow * HH + kt * 32 + q * 8);
#pragma unroll
    for (int kt = 0; kt < 2; ++kt)
      wih[g][kt] = packrow8(Wih + grow * II + kt * 32 + q * 8);
  }

  // biases folded into accumulator init (row = this lane's gate dim)
  f32x4 bias_r, bias_z, bias_hn, bias_xn;
#pragma unroll
  for (int r = 0; r < 4; ++r) {
    const int d = wv * 16 + q * 4 + r;
    bias_r[r]  = bih[d] + bhh[d];
    bias_z[r]  = bih[HH + d] + bhh[HH + d];
    bias_xn[r] = bih[2 * HH + d];
    bias_hn[r] = bhh[2 * HH + d];
  }

  // h0 = 0
  for (int i = tid; i < BC * HROW; i += NTHR) hsh[0][i] = 0;

  float4 xl[4];
  // ---- stage chunk 0 (global fp32 -> bf16 LDS) ----
#pragma unroll
  for (int i = 0; i < 2; ++i) {
    const int L = tid + NTHR * i;
    const int tp = L >> 7, b = (L >> 3) & 15, g8 = L & 7;
    const float* src = xin + (size_t)(b0 + b) * (TT * II) + tp * II + g8 * 8;
    xl[2 * i]     = *(const float4*)src;
    xl[2 * i + 1] = *(const float4*)(src + 4);
  }
#pragma unroll
  for (int i = 0; i < 2; ++i) {
    const int L = tid + NTHR * i;
    const int tp = L >> 7, b = (L >> 3) & 15, g8 = L & 7;
    union { bhalf8 v; unsigned u[4]; } cv;
    cv.u[0] = pack2bf(xl[2 * i].x, xl[2 * i].y);
    cv.u[1] = pack2bf(xl[2 * i].z, xl[2 * i].w);
    cv.u[2] = pack2bf(xl[2 * i + 1].x, xl[2 * i + 1].y);
    cv.u[3] = pack2bf(xl[2 * i + 1].z, xl[2 * i + 1].w);
    *(bhalf8*)&xsh[0][tp][b * XROW + g8 * 8] = cv.v;
  }
  __syncthreads();

  // base pointers hoisted out of the loop
  const short* hrow0 = &hsh[0][c15 * HROW];
  const short* hrow1 = &hsh[1][c15 * HROW];
  short* hw0 = &hsh[1][c15 * HROW + wv * 16 + q * 4];  // write target when t even
  short* hw1 = &hsh[0][c15 * HROW + wv * 16 + q * 4];  // write target when t odd
  const short* xbase = &xsh[0][0][c15 * XROW];

  f32x4 hprev = {0.f, 0.f, 0.f, 0.f};

  // prologue: x-side MFMAs for t=0
  f32x4 ar = bias_r, az = bias_z, ahn = bias_hn, axn = bias_xn;
  {
    bhalf8 xf0 = *(const bhalf8*)(xbase + q * 8);
    bhalf8 xf1 = *(const bhalf8*)(xbase + 32 + q * 8);
    ar  = mfma16(wih[0][0], xf0, ar);  ar  = mfma16(wih[0][1], xf1, ar);
    az  = mfma16(wih[1][0], xf0, az);  az  = mfma16(wih[1][1], xf1, az);
    axn = mfma16(wih[2][0], xf0, axn); axn = mfma16(wih[2][1], xf1, axn);
  }

#pragma unroll 1
  for (int c = 0; c < TT / CHUNK; ++c) {
    const int more = (c + 1 < TT / CHUNK);
    if (more) {  // issue next-chunk global loads early; land mid-chunk
      const int t0 = (c + 1) * CHUNK;
#pragma unroll
      for (int i = 0; i < 2; ++i) {
        const int L = tid + NTHR * i;
        const int tp = L >> 7, b = (L >> 3) & 15, g8 = L & 7;
        const float* src = xin + (size_t)(b0 + b) * (TT * II) + (t0 + tp) * II + g8 * 8;
        xl[2 * i]     = *(const float4*)src;
        xl[2 * i + 1] = *(const float4*)(src + 4);
      }
    }
#pragma unroll
    for (int tp = 0; tp < CHUNK; ++tp) {
      const int t = c * CHUNK + tp;
      const int hb = t & 1;
      // h B-frags (post-barrier critical path starts here)
      const short* hrow = hb ? hrow1 : hrow0;
      bhalf8 hf0 = *(const bhalf8*)(hrow + q * 8);
      bhalf8 hf1 = *(const bhalf8*)(hrow + 32 + q * 8);
      bhalf8 hf2 = *(const bhalf8*)(hrow + 64 + q * 8);
      bhalf8 hf3 = *(const bhalf8*)(hrow + 96 + q * 8);

      ar  = mfma16(whh[0][0], hf0, ar);  ar  = mfma16(whh[0][1], hf1, ar);
      ar  = mfma16(whh[0][2], hf2, ar);  ar  = mfma16(whh[0][3], hf3, ar);
      az  = mfma16(whh[1][0], hf0, az);  az  = mfma16(whh[1][1], hf1, az);
      az  = mfma16(whh[1][2], hf2, az);  az  = mfma16(whh[1][3], hf3, az);
      ahn = mfma16(whh[2][0], hf0, ahn); ahn = mfma16(whh[2][1], hf1, ahn);
      ahn = mfma16(whh[2][2], hf2, ahn); ahn = mfma16(whh[2][3], hf3, ahn);

      // gates: lane-local (4 consecutive h-dims, one batch col); h kept fp32
#pragma unroll
      for (int r = 0; r < 4; ++r) {
        const float rg = __builtin_amdgcn_rcpf(1.0f + __expf(-ar[r]));
        const float zg = __builtin_amdgcn_rcpf(1.0f + __expf(-az[r]));
        const float na = fmaf(rg, ahn[r], axn[r]);
        const float e2 = __expf(na + na);
        const float ng = fmaf(-2.0f, __builtin_amdgcn_rcpf(e2 + 1.0f), 1.0f);
        hprev[r] = fmaf(zg, hprev[r] - ng, ng);
      }

      // publish h_new (4 consecutive dims -> one ds_write_b64)
      union { bhalf4 v; unsigned u[2]; } hp;
      hp.u[0] = pack2bf(hprev[0], hprev[1]);
      hp.u[1] = pack2bf(hprev[2], hprev[3]);
      *(bhalf4*)(hb ? hw1 : hw0) = hp.v;

      // mid-chunk: write next chunk's x into the other LDS buffer
      if (tp == 4 && more) {
#pragma unroll
        for (int i = 0; i < 2; ++i) {
          const int L = tid + NTHR * i;
          const int tpp = L >> 7, b = (L >> 3) & 15, g8 = L & 7;
          union { bhalf8 v; unsigned u[4]; } cv;
          cv.u[0] = pack2bf(xl[2 * i].x, xl[2 * i].y);
          cv.u[1] = pack2bf(xl[2 * i].z, xl[2 * i].w);
          cv.u[2] = pack2bf(xl[2 * i + 1].x, xl[2 * i + 1].y);
          cv.u[3] = pack2bf(xl[2 * i + 1].z, xl[2 * i + 1].w);
          *(bhalf8*)&xsh[(c + 1) & 1][tpp][b * XROW + g8 * 8] = cv.v;
        }
      }

      // prep next step while other waves' h writes land: bias init + x MFMAs
      if (t + 1 < TT) {
        const int nt = t + 1;
        const short* xrow = xbase + ((nt >> 3) & 1) * (CHUNK * BC * XROW)
                                  + (nt & 7) * (BC * XROW);
        bhalf8 xf0 = *(const bhalf8*)(xrow + q * 8);
        bhalf8 xf1 = *(const bhalf8*)(xrow + 32 + q * 8);
        ar = bias_r; az = bias_z; ahn = bias_hn; axn = bias_xn;
        ar  = mfma16(wih[0][0], xf0, ar);  ar  = mfma16(wih[0][1], xf1, ar);
        az  = mfma16(wih[1][0], xf0, az);  az  = mfma16(wih[1][1], xf1, az);
        axn = mfma16(wih[2][0], xf0, axn); axn = mfma16(wih[2][1], xf1, axn);
      }
      bar_lgkm();
    }
  }

  // ---- FC head: out[16,51] from h_T (in hsh[0], since T is even) ----
  for (int idx = tid; idx < BC * 51; idx += NTHR) {
    const int bb = idx / 51;
    const int o = idx - bb * 51;
    const float* wf = Wfc + o * HH;
    const short* hr = &hsh[0][bb * HROW];
    float s = bfc[o];
#pragma unroll
    for (int d = 0; d < HH; d += 4) {
      const float4 wvv = *(const float4*)(wf + d);
      s += bf2f(hr[d]) * wvv.x + bf2f(hr[d + 1]) * wvv.y
         + bf2f(hr[d + 2]) * wvv.z + bf2f(hr[d + 3]) * wvv.w;
    }
    out[(size_t)(b0 + bb) * 51 + o] = s;
  }
}

extern "C" void kernel_launch(void* const* d_in, const int* in_sizes, int n_in,
                              void* d_out, int out_size, void* d_ws, size_t ws_size,
                              hipStream_t stream) {
  const float* xin = (const float*)d_in[0];
  const float* Wih = (const float*)d_in[1];
  const float* Whh = (const float*)d_in[2];
  const float* bih = (const float*)d_in[3];
  const float* bhh = (const float*)d_in[4];
  const float* Wfc = (const float*)d_in[5];
  const float* bfc = (const float*)d_in[6];
  float* o = (float*)d_out;
  hipLaunchKernelGGL(gru_fused, dim3(BATCH / BC), dim3(NTHR), 0, stream,
                     xin, Wih, Whh, bih, bhh, Wfc, bfc, o);
}